// Round 8
// baseline (229.701 us; speedup 1.0000x reference)
//
#include <hip/hip_runtime.h>
#include <cmath>

// Problem constants
constexpr int B_  = 2;
constexpr int T_  = 512;
constexpr int DM_ = 1024;
constexpr int H_  = 16;
constexpr int DH_ = 64;
constexpr int D_  = 32;
constexpr int R_  = 4;
constexpr int BH_ = B_ * H_;   // 32
constexpr int NC_ = 8;         // j-chunks of 64 (2 j-tiles) for split attention

typedef __bf16 bf16x8 __attribute__((ext_vector_type(8)));
typedef float  f32x4  __attribute__((ext_vector_type(4)));
typedef unsigned short u16x8 __attribute__((ext_vector_type(8)));

__device__ __forceinline__ unsigned short f2bf(float f) {
    unsigned u = __float_as_uint(f);
    return (unsigned short)((u + 0x7fffu + ((u >> 16) & 1u)) >> 16);  // RNE
}
__device__ __forceinline__ float bf2f(unsigned short v) {
    return __uint_as_float((unsigned)v << 16);
}

__device__ __forceinline__ void gload16(const void* g, void* l) {
    __builtin_amdgcn_global_load_lds(
        (const __attribute__((address_space(1))) void*)g,
        (__attribute__((address_space(3))) void*)l, 16, 0, 0);
}

// -------------------------------------------------------------------------
// Prep: z=0..3 -> transpose+convert Wq/Wk/Wv/Wo to (N x K) bf16;
//       z=4    -> convert x to bf16 row-major.
// -------------------------------------------------------------------------
__global__ __launch_bounds__(256) void prep_kernel(
    const float* __restrict__ x,
    const float* __restrict__ Wq, const float* __restrict__ Wk,
    const float* __restrict__ Wv, const float* __restrict__ Wo,
    unsigned short* __restrict__ xb,
    unsigned short* __restrict__ wqb, unsigned short* __restrict__ wkb,
    unsigned short* __restrict__ wvb, unsigned short* __restrict__ wob)
{
    const int t = threadIdx.x;
    const int z = blockIdx.z;
    if (z == 4) {
        int base = (blockIdx.y * 16 + blockIdx.x) * 4096 + t * 16;
#pragma unroll
        for (int c = 0; c < 4; ++c) {
            float4 v = *(const float4*)&x[base + c * 4];
            ushort4 o = { f2bf(v.x), f2bf(v.y), f2bf(v.z), f2bf(v.w) };
            *(ushort4*)&xb[base + c * 4] = o;
        }
        return;
    }
    __shared__ __align__(16) unsigned short Ls[64][72];
    const float* W = (z == 0) ? Wq : (z == 1) ? Wk : (z == 2) ? Wv : Wo;
    unsigned short* O = (z == 0) ? wqb : (z == 1) ? wkb : (z == 2) ? wvb : wob;
    const int k0 = blockIdx.x * 64;
    const int n0 = blockIdx.y * 64;
#pragma unroll
    for (int it = 0; it < 4; ++it) {
        int r = it * 16 + (t >> 4);
        int c = (t & 15) * 4;
        float4 v4 = *(const float4*)&W[(size_t)(k0 + r) * DM_ + n0 + c];
        Ls[c + 0][r] = f2bf(v4.x); Ls[c + 1][r] = f2bf(v4.y);
        Ls[c + 2][r] = f2bf(v4.z); Ls[c + 3][r] = f2bf(v4.w);
    }
    __syncthreads();
#pragma unroll
    for (int it = 0; it < 2; ++it) {
        int nl = it * 32 + (t >> 3);
        int kc = (t & 7) * 8;
        *(u16x8*)&O[(size_t)(n0 + nl) * DM_ + k0 + kc] = *(const u16x8*)&Ls[nl][kc];
    }
}

// -------------------------------------------------------------------------
// 64x64-tile bf16 MFMA GEMM, BK=32, 256 thr (unchanged from Round 7).
// -------------------------------------------------------------------------
template <int EPI>
__global__ __launch_bounds__(256) void mfma_gemm64(
    const unsigned short* __restrict__ A,
    const unsigned short* __restrict__ Bt0,
    const unsigned short* __restrict__ Bt1,
    const unsigned short* __restrict__ Bt2,
    float* __restrict__ C0, float* __restrict__ C1, float* __restrict__ C2)
{
    __shared__ __align__(16) unsigned short As[64 * 32];
    __shared__ __align__(16) unsigned short Bs[64 * 32];
    const int tid  = threadIdx.x;
    const int lane = tid & 63;
    const int w    = tid >> 6;
    const int wm   = (w & 1) * 32;
    const int wn   = (w >> 1) * 32;

    const int bm = blockIdx.y * 64;
    int bn;
    const unsigned short* Bt;
    float* C;
    if (EPI == 0) {
        int n0 = blockIdx.x * 64;
        int which = n0 >> 10;
        bn = n0 & 1023;
        Bt = (which == 0) ? Bt0 : (which == 1) ? Bt1 : Bt2;
        C  = (which == 0) ? C0  : (which == 1) ? C1  : C2;
    } else {
        bn = blockIdx.x * 64;
        Bt = Bt0; C = C0;
    }

    f32x4 acc[2][2] = {};
    const int sr = tid >> 2;
    const int sc = (tid & 3) * 8;
    const unsigned short* Ap = A  + (size_t)(bm + sr) * DM_ + sc;
    const unsigned short* Bp = Bt + (size_t)(bn + sr) * DM_ + sc;
    unsigned short* AsP = &As[sr * 32 + sc];
    unsigned short* BsP = &Bs[sr * 32 + sc];
    const int fr = lane & 15;
    const int fq = (lane >> 4) * 8;

    for (int k0 = 0; k0 < DM_; k0 += 32) {
        gload16(Ap + k0, AsP);
        gload16(Bp + k0, BsP);
        __syncthreads();
        bf16x8 af[2], bfr[2];
#pragma unroll
        for (int i = 0; i < 2; ++i) {
            af[i]  = *(const bf16x8*)&As[(wm + i * 16 + fr) * 32 + fq];
            bfr[i] = *(const bf16x8*)&Bs[(wn + i * 16 + fr) * 32 + fq];
        }
#pragma unroll
        for (int mi = 0; mi < 2; ++mi)
#pragma unroll
            for (int ni = 0; ni < 2; ++ni)
                acc[mi][ni] = __builtin_amdgcn_mfma_f32_16x16x32_bf16(
                    af[mi], bfr[ni], acc[mi][ni], 0, 0, 0);
        __syncthreads();
    }

#pragma unroll
    for (int mi = 0; mi < 2; ++mi)
#pragma unroll
        for (int ni = 0; ni < 2; ++ni) {
            f32x4 a = acc[mi][ni];
            int col = bn + wn + ni * 16 + (lane & 15);
#pragma unroll
            for (int r = 0; r < 4; ++r) {
                int row = bm + wm + mi * 16 + (lane >> 4) * 4 + r;
                if (EPI == 0) {
                    int h = col >> 6, d = col & 63;
                    int bb = row >> 9, tt = row & (T_ - 1);
                    C[(((size_t)bb * H_ + h) * T_ + tt) * DH_ + d] = a[r];
                } else {
                    C[(size_t)row * DM_ + col] = a[r];
                }
            }
        }
}

// -------------------------------------------------------------------------
// Per-row features, q-side and k-side fused (unchanged).
// -------------------------------------------------------------------------
__global__ __launch_bounds__(256) void feat_both(
    const float* __restrict__ q_raw, const float* __restrict__ k_raw,
    const float* __restrict__ Wqm,   const float* __restrict__ Wkm,
    const float* __restrict__ Wmetric,
    float* __restrict__ qm, float* __restrict__ km,
    float* __restrict__ q2, float* __restrict__ k2,
    float* __restrict__ Ug, float* __restrict__ Uqg)
{
    const bool QSIDE = (blockIdx.y == 0);
    const float* raw = QSIDE ? q_raw : k_raw;
    const float* Wm  = QSIDE ? Wqm   : Wkm;
    float* fm = QSIDE ? qm : km;
    float* f2 = QSIDE ? q2 : k2;

    __shared__ float qrs[4][64];
    __shared__ float qms[4][32];
    __shared__ float Us[4][128];
    const int tid  = threadIdx.x;
    const int w    = tid >> 6;
    const int lane = tid & 63;
    const int row  = blockIdx.x * 4 + w;
    const int t    = row & (T_ - 1);

    float rv = raw[(size_t)row * 64 + lane];
    int   fi = lane & 31;
    float ang = (float)t * expf((float)fi * -0.28782313662425575f);
    float s, c;
    sincosf(ang, &s, &c);
    float partner = __shfl_xor(rv, 32);
    float qr = (lane < 32) ? (rv * c - partner * s) : (partner * s + rv * c);
    qrs[w][lane] = qr;
    __syncthreads();

    if (lane < 32) {
        float acc = 0.f;
#pragma unroll 8
        for (int d = 0; d < 64; ++d) acc += qrs[w][d] * Wm[d * 32 + lane];
        float qv = 1.0f / (1.0f + __expf(-acc));
        qms[w][lane] = qv;
        fm[(size_t)row * 32 + lane] = qv;
    }
    __syncthreads();
    if (lane == 0) {
        float acc = 0.f;
#pragma unroll
        for (int m = 0; m < 32; ++m) acc += qms[w][m] * qms[w][m];
        f2[row] = acc;
    }
    if (QSIDE) {
        float a0 = 0.f, a1 = 0.f;
#pragma unroll 8
        for (int m = 0; m < 32; ++m) {
            float qv = qms[w][m];
            a0 += qv * Wmetric[m * 128 + lane];
            a1 += qv * Wmetric[m * 128 + 64 + lane];
        }
        Us[w][lane] = a0; Us[w][64 + lane] = a1;
        Ug[(size_t)row * 128 + lane]      = a0;
        Ug[(size_t)row * 128 + 64 + lane] = a1;
        __syncthreads();
        if (lane < 4) {
            float acc = 0.f;
#pragma unroll
            for (int d = 0; d < 32; ++d) acc += Us[w][d * 4 + lane] * qms[w][d];
            Uqg[(size_t)row * 4 + lane] = acc;
        }
    }
}

// -------------------------------------------------------------------------
// Split-j fused attention, chunk = 64 j (<=2 j-tiles serial per block).
// Block (c, itile, bh) live iff 2c <= itile.  Partial O stored in bf16.
// -------------------------------------------------------------------------
__global__ __launch_bounds__(256) void fused_attn_split(
    const float* __restrict__ qm, const float* __restrict__ km,
    const float* __restrict__ q2, const float* __restrict__ k2,
    const float* __restrict__ Ug, const float* __restrict__ Uqg,
    const float* __restrict__ temp_p, const float* __restrict__ v,
    unsigned short* __restrict__ Opart, float* __restrict__ Mpart,
    float* __restrict__ Lpart)
{
    __shared__ __align__(16) float qm_s[32][33];
    __shared__ __align__(16) float U_s[32][132];
    __shared__ __align__(16) float Uq_s[32][4];
    __shared__ float q2_s[32];
    __shared__ __align__(16) float kmT_s[32][36];
    __shared__ float k2_s[32];
    __shared__ __align__(16) float v_s[32][64];
    __shared__ float s_tile[32][33];

    const int c     = blockIdx.x;
    const int itile = blockIdx.y;
    const int bh    = blockIdx.z;
    if (c * 2 > itile) return;                        // dead block
    const int ntl = min(itile - c * 2, 1) + 1;        // 1..2 j-tiles
    const int i0  = itile * 32;
    const int tid = threadIdx.x;

    for (int e = tid; e < 32 * 32; e += 256) {
        int ii = e >> 5, m = e & 31;
        qm_s[ii][m] = qm[((size_t)bh * T_ + i0 + ii) * 32 + m];
    }
    for (int e = tid; e < 32 * 128; e += 256) {
        int ii = e >> 7, n = e & 127;
        U_s[ii][n] = Ug[((size_t)bh * T_ + i0 + ii) * 128 + n];
    }
    if (tid < 128) Uq_s[tid >> 2][tid & 3] = Uqg[((size_t)bh * T_ + i0) * 4 + tid];
    if (tid < 32)  q2_s[tid] = q2[(size_t)bh * T_ + i0 + tid];

    const float inv_temp = 1.0f / fmaxf(temp_p[0], 0.5f);

    const int ii_s = tid & 31, js = tid >> 5;
    const int ii_u = tid >> 3, ds = tid & 7;

    float m_run = -1e30f, l_run = 0.f;
    float O[8] = {};

    for (int jt = 0; jt < ntl; ++jt) {
        const int j0 = (c * 2 + jt) * 32;
        __syncthreads();
        {
            int jr = tid >> 3, c4 = (tid & 7) * 4;
            float4 g = *(const float4*)&km[((size_t)bh * T_ + j0 + jr) * 32 + c4];
            kmT_s[c4 + 0][jr] = g.x; kmT_s[c4 + 1][jr] = g.y;
            kmT_s[c4 + 2][jr] = g.z; kmT_s[c4 + 3][jr] = g.w;
        }
        if (tid < 32) k2_s[tid] = k2[(size_t)bh * T_ + j0 + tid];
#pragma unroll
        for (int e = tid; e < 512; e += 256) {
            int jr = e >> 4, c4 = (e & 15) * 4;
            *(float4*)&v_s[jr][c4] =
                *(const float4*)&v[((size_t)bh * T_ + j0 + jr) * 64 + c4];
        }
        __syncthreads();

        {
            float qk[4] = {};
            float ur[4][4] = {};
#pragma unroll 8
            for (int d = 0; d < 32; ++d) {
                float4 kd = *(const float4*)&kmT_s[d][js * 4];
                float  qv = qm_s[ii_s][d];
                float4 uv = *(const float4*)&U_s[ii_s][4 * d];
                float  kc[4] = {kd.x, kd.y, kd.z, kd.w};
#pragma unroll
                for (int cc = 0; cc < 4; ++cc) {
                    qk[cc] = fmaf(qv, kc[cc], qk[cc]);
                    ur[cc][0] = fmaf(uv.x, kc[cc], ur[cc][0]);
                    ur[cc][1] = fmaf(uv.y, kc[cc], ur[cc][1]);
                    ur[cc][2] = fmaf(uv.z, kc[cc], ur[cc][2]);
                    ur[cc][3] = fmaf(uv.w, kc[cc], ur[cc][3]);
                }
            }
            const float q2v = q2_s[ii_s];
            const float uq0 = Uq_s[ii_s][0], uq1 = Uq_s[ii_s][1];
            const float uq2 = Uq_s[ii_s][2], uq3 = Uq_s[ii_s][3];
#pragma unroll
            for (int cc = 0; cc < 4; ++cc) {
                int jj = js * 4 + cc;
                float e0 = uq0 - ur[cc][0], e1 = uq1 - ur[cc][1];
                float e2 = uq2 - ur[cc][2], e3 = uq3 - ur[cc][3];
                float dist = q2v + k2_s[jj] - 2.f * qk[cc]
                           + e0 * e0 + e1 * e1 + e2 * e2 + e3 * e3;
                float s = -fmaxf(dist, 0.f) * inv_temp;
                if (j0 + jj > i0 + ii_s) s = -1e30f;
                s_tile[ii_s][jj] = s;
            }
        }
        __syncthreads();

        {
            float mt = -1e30f;
#pragma unroll 8
            for (int jj = 0; jj < 32; ++jj) mt = fmaxf(mt, s_tile[ii_u][jj]);
            float mnew  = fmaxf(m_run, mt);
            float alpha = __expf(m_run - mnew);
            l_run *= alpha;
#pragma unroll
            for (int dd = 0; dd < 8; ++dd) O[dd] *= alpha;
#pragma unroll 4
            for (int jj = 0; jj < 32; ++jj) {
                float p = __expf(s_tile[ii_u][jj] - mnew);
                l_run += p;
                float4 v0 = *(const float4*)&v_s[jj][ds * 8];
                float4 v1 = *(const float4*)&v_s[jj][ds * 8 + 4];
                O[0] = fmaf(p, v0.x, O[0]); O[1] = fmaf(p, v0.y, O[1]);
                O[2] = fmaf(p, v0.z, O[2]); O[3] = fmaf(p, v0.w, O[3]);
                O[4] = fmaf(p, v1.x, O[4]); O[5] = fmaf(p, v1.y, O[5]);
                O[6] = fmaf(p, v1.z, O[6]); O[7] = fmaf(p, v1.w, O[7]);
            }
            m_run = mnew;
        }
    }

    // epilogue: unnormalized O in bf16, m/l fp32
    const int i = i0 + ii_u;
    const size_t rowix = ((size_t)c * BH_ + bh) * T_ + i;
    u16x8 o;
#pragma unroll
    for (int dd = 0; dd < 8; ++dd) o[dd] = f2bf(O[dd]);
    *(u16x8*)&Opart[rowix * 64 + ds * 8] = o;
    if (ds == 0) { Mpart[rowix] = m_run; Lpart[rowix] = l_run; }
}

// -------------------------------------------------------------------------
// Merge <=8 partials per row; write ctx bf16 (b,t,c).
// -------------------------------------------------------------------------
__global__ __launch_bounds__(256) void merge_attn(
    const unsigned short* __restrict__ Opart, const float* __restrict__ Mpart,
    const float* __restrict__ Lpart, unsigned short* __restrict__ ctxb)
{
    const int tid = threadIdx.x;
    const int itile = blockIdx.x, bh = blockIdx.y;
    const int ii = tid >> 3, ds = tid & 7;
    const int i = itile * 32 + ii;
    const int nc = (i >> 6) + 1;          // chunks of 64

    float mx = -1e30f;
    float mv[NC_];
    for (int c = 0; c < nc; ++c) {
        mv[c] = Mpart[((size_t)c * BH_ + bh) * T_ + i];
        mx = fmaxf(mx, mv[c]);
    }
    float lsum = 0.f;
    float O[8] = {};
    for (int c = 0; c < nc; ++c) {
        const size_t rowix = ((size_t)c * BH_ + bh) * T_ + i;
        float w = __expf(mv[c] - mx);
        lsum = fmaf(Lpart[rowix], w, lsum);
        u16x8 ov = *(const u16x8*)&Opart[rowix * 64 + ds * 8];
#pragma unroll
        for (int dd = 0; dd < 8; ++dd) O[dd] = fmaf(w, bf2f(ov[dd]), O[dd]);
    }
    const float inv_l = 1.0f / lsum;
    const int b = bh >> 4, h = bh & 15;
    u16x8 o;
#pragma unroll
    for (int dd = 0; dd < 8; ++dd) o[dd] = f2bf(O[dd] * inv_l);
    *(u16x8*)&ctxb[((size_t)b * T_ + i) * DM_ + h * 64 + ds * 8] = o;
}

// -------------------------------------------------------------------------
extern "C" void kernel_launch(void* const* d_in, const int* in_sizes, int n_in,
                              void* d_out, int out_size, void* d_ws, size_t ws_size,
                              hipStream_t stream)
{
    const float* x       = (const float*)d_in[0];
    const float* Wq      = (const float*)d_in[1];
    const float* Wk      = (const float*)d_in[2];
    const float* Wv      = (const float*)d_in[3];
    const float* Wo      = (const float*)d_in[4];
    const float* Wqm     = (const float*)d_in[5];
    const float* Wkm     = (const float*)d_in[6];
    const float* Wmetric = (const float*)d_in[7];
    const float* temp    = (const float*)d_in[8];
    float* out = (float*)d_out;
    float* ws  = (float*)d_ws;

    // fp32 workspace (floats), 25.6 MB
    float* q_raw = ws;                                  // 1,048,576
    float* k_raw = q_raw + (size_t)BH_ * T_ * DH_;      // 1,048,576
    float* v     = k_raw + (size_t)BH_ * T_ * DH_;      // 1,048,576
    float* qm    = v     + (size_t)BH_ * T_ * DH_;      //   524,288
    float* km    = qm    + (size_t)BH_ * T_ * D_;       //   524,288
    float* q2    = km    + (size_t)BH_ * T_ * D_;       //    16,384
    float* k2    = q2    + (size_t)BH_ * T_;            //    16,384
    float* U     = k2    + (size_t)BH_ * T_;            // 2,097,152
    float* Uq    = U     + (size_t)BH_ * T_ * D_ * R_;  //    65,536
    // bf16 GEMM inputs (8 MB), dead after qkv gemm
    unsigned short* xb  = (unsigned short*)(Uq + (size_t)BH_ * T_ * R_);
    unsigned short* wqb = xb  + (size_t)DM_ * DM_;
    unsigned short* wkb = wqb + (size_t)DM_ * DM_;
    unsigned short* wvb = wkb + (size_t)DM_ * DM_;
    unsigned short* ctxb = (unsigned short*)q_raw;      // q_raw dead after feat
    // split-attention partials overlay the dead bf16-input region:
    //   Opart bf16 16.8 MB + M/L fp32 1 MB   (written during attention)
    unsigned short* Opart = xb;
    float* Mpart = (float*)(Opart + (size_t)NC_ * BH_ * T_ * DH_);
    float* Lpart = Mpart + (size_t)NC_ * BH_ * T_;
    // Wo bf16-T after partials (written in prep, read only by final gemm)
    unsigned short* wob = (unsigned short*)(Lpart + (size_t)NC_ * BH_ * T_);
    // total footprint ~45.4 MB (< 59.1 MB proven in Round 2)

    prep_kernel<<<dim3(16, 16, 5), 256, 0, stream>>>(
        x, Wq, Wk, Wv, Wo, xb, wqb, wkb, wvb, wob);
    mfma_gemm64<0><<<dim3(48, 16), 256, 0, stream>>>(
        xb, wqb, wkb, wvb, q_raw, k_raw, v);
    feat_both<<<dim3(BH_ * T_ / 4, 2), 256, 0, stream>>>(
        q_raw, k_raw, Wqm, Wkm, Wmetric, qm, km, q2, k2, U, Uq);
    fused_attn_split<<<dim3(NC_, 16, BH_), 256, 0, stream>>>(
        qm, km, q2, k2, U, Uq, temp, v, Opart, Mpart, Lpart);
    merge_attn<<<dim3(16, BH_), 256, 0, stream>>>(Opart, Mpart, Lpart, ctxb);
    mfma_gemm64<1><<<dim3(16, 16), 256, 0, stream>>>(
        ctxb, wob, nullptr, nullptr, out, nullptr, nullptr);
}

// Round 9
// 156.166 us; speedup vs baseline: 1.4709x; 1.4709x over previous
//
#include <hip/hip_runtime.h>
#include <cmath>

// Problem constants
constexpr int B_  = 2;
constexpr int T_  = 512;
constexpr int DM_ = 1024;
constexpr int H_  = 16;
constexpr int DH_ = 64;
constexpr int D_  = 32;
constexpr int R_  = 4;
constexpr int BH_ = B_ * H_;   // 32

typedef __bf16 bf16x8 __attribute__((ext_vector_type(8)));
typedef float  f32x4  __attribute__((ext_vector_type(4)));
typedef unsigned short u16x8 __attribute__((ext_vector_type(8)));

__device__ __forceinline__ unsigned short f2bf(float f) {
    unsigned u = __float_as_uint(f);
    return (unsigned short)((u + 0x7fffu + ((u >> 16) & 1u)) >> 16);  // RNE
}
__device__ __forceinline__ float bf2f(unsigned short v) {
    return __uint_as_float((unsigned)v << 16);
}

__device__ __forceinline__ void gload16(const void* g, void* l) {
    __builtin_amdgcn_global_load_lds(
        (const __attribute__((address_space(1))) void*)g,
        (__attribute__((address_space(3))) void*)l, 16, 0, 0);
}

// -------------------------------------------------------------------------
// Prep: z=0..3 -> transpose+convert Wq/Wk/Wv/Wo to (N x K) bf16;
//       z=4    -> convert x to bf16 row-major.  (unchanged)
// -------------------------------------------------------------------------
__global__ __launch_bounds__(256) void prep_kernel(
    const float* __restrict__ x,
    const float* __restrict__ Wq, const float* __restrict__ Wk,
    const float* __restrict__ Wv, const float* __restrict__ Wo,
    unsigned short* __restrict__ xb,
    unsigned short* __restrict__ wqb, unsigned short* __restrict__ wkb,
    unsigned short* __restrict__ wvb, unsigned short* __restrict__ wob)
{
    const int t = threadIdx.x;
    const int z = blockIdx.z;
    if (z == 4) {
        int base = (blockIdx.y * 16 + blockIdx.x) * 4096 + t * 16;
#pragma unroll
        for (int c = 0; c < 4; ++c) {
            float4 v = *(const float4*)&x[base + c * 4];
            ushort4 o = { f2bf(v.x), f2bf(v.y), f2bf(v.z), f2bf(v.w) };
            *(ushort4*)&xb[base + c * 4] = o;
        }
        return;
    }
    __shared__ __align__(16) unsigned short Ls[64][72];
    const float* W = (z == 0) ? Wq : (z == 1) ? Wk : (z == 2) ? Wv : Wo;
    unsigned short* O = (z == 0) ? wqb : (z == 1) ? wkb : (z == 2) ? wvb : wob;
    const int k0 = blockIdx.x * 64;
    const int n0 = blockIdx.y * 64;
#pragma unroll
    for (int it = 0; it < 4; ++it) {
        int r = it * 16 + (t >> 4);
        int c = (t & 15) * 4;
        float4 v4 = *(const float4*)&W[(size_t)(k0 + r) * DM_ + n0 + c];
        Ls[c + 0][r] = f2bf(v4.x); Ls[c + 1][r] = f2bf(v4.y);
        Ls[c + 2][r] = f2bf(v4.z); Ls[c + 3][r] = f2bf(v4.w);
    }
    __syncthreads();
#pragma unroll
    for (int it = 0; it < 2; ++it) {
        int nl = it * 32 + (t >> 3);
        int kc = (t & 7) * 8;
        *(u16x8*)&O[(size_t)(n0 + nl) * DM_ + k0 + kc] = *(const u16x8*)&Ls[nl][kc];
    }
}

// -------------------------------------------------------------------------
// 64x64-tile bf16 MFMA GEMM.  EPI==0: q/k -> fp32 head layout, v -> bf16
// transposed vT[bh][dh][t].  EPI==1: plain fp32 C.
// -------------------------------------------------------------------------
template <int EPI>
__global__ __launch_bounds__(256) void mfma_gemm64(
    const unsigned short* __restrict__ A,
    const unsigned short* __restrict__ Bt0,
    const unsigned short* __restrict__ Bt1,
    const unsigned short* __restrict__ Bt2,
    float* __restrict__ C0, float* __restrict__ C1,
    unsigned short* __restrict__ vT)
{
    __shared__ __align__(16) unsigned short As[64 * 32];
    __shared__ __align__(16) unsigned short Bs[64 * 32];
    const int tid  = threadIdx.x;
    const int lane = tid & 63;
    const int w    = tid >> 6;
    const int wm   = (w & 1) * 32;
    const int wn   = (w >> 1) * 32;

    const int bm = blockIdx.y * 64;
    int bn, which = 0;
    const unsigned short* Bt;
    if (EPI == 0) {
        int n0 = blockIdx.x * 64;
        which = n0 >> 10;
        bn = n0 & 1023;
        Bt = (which == 0) ? Bt0 : (which == 1) ? Bt1 : Bt2;
    } else {
        bn = blockIdx.x * 64;
        Bt = Bt0;
    }

    f32x4 acc[2][2] = {};
    const int sr = tid >> 2;
    const int sc = (tid & 3) * 8;
    const unsigned short* Ap = A  + (size_t)(bm + sr) * DM_ + sc;
    const unsigned short* Bp = Bt + (size_t)(bn + sr) * DM_ + sc;
    unsigned short* AsP = &As[sr * 32 + sc];
    unsigned short* BsP = &Bs[sr * 32 + sc];
    const int fr = lane & 15;
    const int fq = (lane >> 4) * 8;

    for (int k0 = 0; k0 < DM_; k0 += 32) {
        gload16(Ap + k0, AsP);
        gload16(Bp + k0, BsP);
        __syncthreads();
        bf16x8 af[2], bfr[2];
#pragma unroll
        for (int i = 0; i < 2; ++i) {
            af[i]  = *(const bf16x8*)&As[(wm + i * 16 + fr) * 32 + fq];
            bfr[i] = *(const bf16x8*)&Bs[(wn + i * 16 + fr) * 32 + fq];
        }
#pragma unroll
        for (int mi = 0; mi < 2; ++mi)
#pragma unroll
            for (int ni = 0; ni < 2; ++ni)
                acc[mi][ni] = __builtin_amdgcn_mfma_f32_16x16x32_bf16(
                    af[mi], bfr[ni], acc[mi][ni], 0, 0, 0);
        __syncthreads();
    }

#pragma unroll
    for (int mi = 0; mi < 2; ++mi)
#pragma unroll
        for (int ni = 0; ni < 2; ++ni) {
            f32x4 a = acc[mi][ni];
            int col = bn + wn + ni * 16 + (lane & 15);
#pragma unroll
            for (int r = 0; r < 4; ++r) {
                int row = bm + wm + mi * 16 + (lane >> 4) * 4 + r;
                if (EPI == 0) {
                    int h = col >> 6, d = col & 63;
                    int bb = row >> 9, tt = row & (T_ - 1);
                    if (which == 2) {
                        // vT[bh][dh][t] bf16 for the attention PV MFMA B-frags
                        vT[(((size_t)bb * H_ + h) * DH_ + d) * T_ + tt] = f2bf(a[r]);
                    } else {
                        float* C = (which == 0) ? C0 : C1;
                        C[(((size_t)bb * H_ + h) * T_ + tt) * DH_ + d] = a[r];
                    }
                } else {
                    C0[(size_t)row * DM_ + col] = a[r];
                }
            }
        }
}

// -------------------------------------------------------------------------
// Per-row features.  Q-side: a = qm + U·Uq (hi/lo bf16), Urb[r][t][d] bf16,
// q2' = |qm|^2 + |Uq|^2.  K-side: km hi/lo bf16, k2.
// -------------------------------------------------------------------------
__global__ __launch_bounds__(256) void feat_both(
    const float* __restrict__ q_raw, const float* __restrict__ k_raw,
    const float* __restrict__ Wqm,   const float* __restrict__ Wkm,
    const float* __restrict__ Wmetric,
    unsigned short* __restrict__ a_hi, unsigned short* __restrict__ a_lo,
    unsigned short* __restrict__ km_hi, unsigned short* __restrict__ km_lo,
    float* __restrict__ q2p, float* __restrict__ k2,
    unsigned short* __restrict__ Urb)
{
    const bool QSIDE = (blockIdx.y == 0);
    const float* raw = QSIDE ? q_raw : k_raw;
    const float* Wm  = QSIDE ? Wqm   : Wkm;

    __shared__ float qrs[4][64];
    __shared__ float qms[4][32];
    __shared__ float Us[4][128];
    __shared__ float Uqs[4][4];
    const int tid  = threadIdx.x;
    const int w    = tid >> 6;
    const int lane = tid & 63;
    const int row  = blockIdx.x * 4 + w;       // bh*T + t
    const int t    = row & (T_ - 1);
    const int bh   = row >> 9;

    float rv = raw[(size_t)row * 64 + lane];
    int   fi = lane & 31;
    float ang = (float)t * expf((float)fi * -0.28782313662425575f);
    float s, c;
    sincosf(ang, &s, &c);
    float partner = __shfl_xor(rv, 32);
    float qr = (lane < 32) ? (rv * c - partner * s) : (partner * s + rv * c);
    qrs[w][lane] = qr;
    __syncthreads();

    if (lane < 32) {
        float acc = 0.f;
#pragma unroll 8
        for (int d = 0; d < 64; ++d) acc += qrs[w][d] * Wm[d * 32 + lane];
        qms[w][lane] = 1.0f / (1.0f + __expf(-acc));
    }
    __syncthreads();

    if (QSIDE) {
        // U (128-wide) from qm
        float a0 = 0.f, a1 = 0.f;
#pragma unroll 8
        for (int m = 0; m < 32; ++m) {
            float qv = qms[w][m];
            a0 += qv * Wmetric[m * 128 + lane];
            a1 += qv * Wmetric[m * 128 + 64 + lane];
        }
        Us[w][lane] = a0; Us[w][64 + lane] = a1;
        // Urb[bh][r][t][d]: e0 = lane (d=lane>>2, r=lane&3), e1 = lane+64
        {
            int r0 = lane & 3, d0 = lane >> 2;
            int d1 = 16 + (lane >> 2);
            Urb[(((size_t)bh * R_ + r0) * T_ + t) * D_ + d0] = f2bf(a0);
            Urb[(((size_t)bh * R_ + r0) * T_ + t) * D_ + d1] = f2bf(a1);
        }
        __syncthreads();
        if (lane < 4) {
            float acc = 0.f;
#pragma unroll
            for (int d = 0; d < 32; ++d) acc += Us[w][d * 4 + lane] * qms[w][d];
            Uqs[w][lane] = acc;
        }
        __syncthreads();
        if (lane < 32) {
            float b = Uqs[w][0] * Us[w][lane * 4 + 0]
                    + Uqs[w][1] * Us[w][lane * 4 + 1]
                    + Uqs[w][2] * Us[w][lane * 4 + 2]
                    + Uqs[w][3] * Us[w][lane * 4 + 3];
            float a = qms[w][lane] + b;
            unsigned short hi = f2bf(a);
            unsigned short lo = f2bf(a - bf2f(hi));
            size_t off = (size_t)row * 32 + lane;
            a_hi[off] = hi; a_lo[off] = lo;
        }
        if (lane == 0) {
            float acc = 0.f;
#pragma unroll
            for (int m = 0; m < 32; ++m) acc += qms[w][m] * qms[w][m];
#pragma unroll
            for (int r = 0; r < 4; ++r) acc += Uqs[w][r] * Uqs[w][r];
            q2p[row] = acc;
        }
    } else {
        if (lane < 32) {
            float v = qms[w][lane];
            unsigned short hi = f2bf(v);
            unsigned short lo = f2bf(v - bf2f(hi));
            size_t off = (size_t)row * 32 + lane;
            km_hi[off] = hi; km_lo[off] = lo;
        }
        if (lane == 0) {
            float acc = 0.f;
#pragma unroll
            for (int m = 0; m < 32; ++m) acc += qms[w][m] * qms[w][m];
            k2[row] = acc;
        }
    }
}

// -------------------------------------------------------------------------
// MFMA attention: block (itile, bh); wave w owns j-tiles jt = w, w+4, ...
// dist = q2'_i + k2_j - 2*(a.km) + sum_r (U_r.km)^2 ;  softmax with m=0
// (all scores <= 0, so no online max).  P,V bf16 MFMA for PV.  Additive
// cross-wave merge via LDS (no barriers inside the per-wave j-loop!).
// -------------------------------------------------------------------------
constexpr int PROW = 40;   // P_lds row pitch (u16): 16B-aligned frags + bank spread
__global__ __launch_bounds__(256) void attn_mfma(
    const unsigned short* __restrict__ a_hi, const unsigned short* __restrict__ a_lo,
    const unsigned short* __restrict__ km_hi, const unsigned short* __restrict__ km_lo,
    const unsigned short* __restrict__ Urb,
    const float* __restrict__ q2p, const float* __restrict__ k2,
    const float* __restrict__ temp_p, const unsigned short* __restrict__ vT,
    unsigned short* __restrict__ ctxb)
{
    __shared__ __align__(16) unsigned short P_lds[4][32 * PROW];
    __shared__ __align__(16) float OP[4][32][64];
    __shared__ float ML[4][32];

    const int itile = blockIdx.x, bh = blockIdx.y;
    const int i0 = itile * 32;
    const int tid = threadIdx.x, w = tid >> 6, lane = tid & 63;
    const int l15 = lane & 15, quad = lane >> 4;

    const float inv_temp = 1.0f / fmaxf(temp_p[0], 0.5f);

    // A-frags (i-tile constant): A[m=l15][k=quad*8+j]
    bf16x8 Ahi[2], Alo[2], Aur[4][2];
#pragma unroll
    for (int mi = 0; mi < 2; ++mi) {
        size_t ab = ((size_t)bh * T_ + i0 + mi * 16 + l15) * 32 + quad * 8;
        Ahi[mi] = *(const bf16x8*)&a_hi[ab];
        Alo[mi] = *(const bf16x8*)&a_lo[ab];
#pragma unroll
        for (int r = 0; r < 4; ++r)
            Aur[r][mi] = *(const bf16x8*)
                &Urb[(((size_t)bh * R_ + r) * T_ + i0 + mi * 16 + l15) * 32 + quad * 8];
    }
    float q2r[2][4];
#pragma unroll
    for (int mi = 0; mi < 2; ++mi)
#pragma unroll
        for (int rg = 0; rg < 4; ++rg)
            q2r[mi][rg] = q2p[(size_t)bh * T_ + i0 + mi * 16 + quad * 4 + rg];

    f32x4 Oacc[2][4] = {};
    float psum[2][4] = {};

    for (int jt = w; jt <= itile; jt += 4) {
        const int j0 = jt * 32;
        bf16x8 Bhi[2], Blo[2];
#pragma unroll
        for (int ni = 0; ni < 2; ++ni) {
            size_t kb = ((size_t)bh * T_ + j0 + ni * 16 + l15) * 32 + quad * 8;
            Bhi[ni] = *(const bf16x8*)&km_hi[kb];
            Blo[ni] = *(const bf16x8*)&km_lo[kb];
        }
        // qk = a.km via hi/lo split (3 passes -> ~fp32 accuracy)
        f32x4 acc[2][2] = {};
#pragma unroll
        for (int mi = 0; mi < 2; ++mi)
#pragma unroll
            for (int ni = 0; ni < 2; ++ni) {
                acc[mi][ni] = __builtin_amdgcn_mfma_f32_16x16x32_bf16(
                    Alo[mi], Bhi[ni], acc[mi][ni], 0, 0, 0);
                acc[mi][ni] = __builtin_amdgcn_mfma_f32_16x16x32_bf16(
                    Ahi[mi], Blo[ni], acc[mi][ni], 0, 0, 0);
                acc[mi][ni] = __builtin_amdgcn_mfma_f32_16x16x32_bf16(
                    Ahi[mi], Bhi[ni], acc[mi][ni], 0, 0, 0);
            }
        // sum_r (U_r.km)^2
        f32x4 sq[2][2] = {};
#pragma unroll
        for (int r = 0; r < 4; ++r) {
            f32x4 ar[2][2] = {};
#pragma unroll
            for (int mi = 0; mi < 2; ++mi)
#pragma unroll
                for (int ni = 0; ni < 2; ++ni)
                    ar[mi][ni] = __builtin_amdgcn_mfma_f32_16x16x32_bf16(
                        Aur[r][mi], Bhi[ni], ar[mi][ni], 0, 0, 0);
#pragma unroll
            for (int mi = 0; mi < 2; ++mi)
#pragma unroll
                for (int ni = 0; ni < 2; ++ni)
                    sq[mi][ni] += ar[mi][ni] * ar[mi][ni];
        }
        float k2c[2];
#pragma unroll
        for (int ni = 0; ni < 2; ++ni)
            k2c[ni] = k2[(size_t)bh * T_ + j0 + ni * 16 + l15];
        const bool diag = (jt == itile);
#pragma unroll
        for (int mi = 0; mi < 2; ++mi)
#pragma unroll
            for (int ni = 0; ni < 2; ++ni)
#pragma unroll
                for (int rg = 0; rg < 4; ++rg) {
                    float dist = q2r[mi][rg] + k2c[ni]
                               - 2.f * acc[mi][ni][rg] + sq[mi][ni][rg];
                    float sc = -fmaxf(dist, 0.f) * inv_temp;
                    if (diag && (ni * 16 + l15) > (mi * 16 + quad * 4 + rg))
                        sc = -1e30f;
                    float p = __expf(sc);          // scores <= 0: m=0 softmax exact
                    psum[mi][rg] += p;
                    P_lds[w][(mi * 16 + quad * 4 + rg) * PROW + ni * 16 + l15] = f2bf(p);
                }
        // PV via MFMA: P (A-layout from LDS), V (B-frags from global vT)
        bf16x8 Pf[2], Vf[4];
#pragma unroll
        for (int mi = 0; mi < 2; ++mi)
            Pf[mi] = *(const bf16x8*)&P_lds[w][(mi * 16 + l15) * PROW + quad * 8];
#pragma unroll
        for (int n4 = 0; n4 < 4; ++n4)
            Vf[n4] = *(const bf16x8*)
                &vT[((size_t)bh * DH_ + n4 * 16 + l15) * T_ + j0 + quad * 8];
#pragma unroll
        for (int mi = 0; mi < 2; ++mi)
#pragma unroll
            for (int n4 = 0; n4 < 4; ++n4)
                Oacc[mi][n4] = __builtin_amdgcn_mfma_f32_16x16x32_bf16(
                    Pf[mi], Vf[n4], Oacc[mi][n4], 0, 0, 0);
    }

    // per-row sum over the 16 col-lanes
#pragma unroll
    for (int mi = 0; mi < 2; ++mi)
#pragma unroll
        for (int rg = 0; rg < 4; ++rg) {
            float v = psum[mi][rg];
            v += __shfl_xor(v, 1); v += __shfl_xor(v, 2);
            v += __shfl_xor(v, 4); v += __shfl_xor(v, 8);
            psum[mi][rg] = v;
        }
    if (l15 == 0)
#pragma unroll
        for (int mi = 0; mi < 2; ++mi)
#pragma unroll
            for (int rg = 0; rg < 4; ++rg)
                ML[w][mi * 16 + quad * 4 + rg] = psum[mi][rg];
#pragma unroll
    for (int mi = 0; mi < 2; ++mi)
#pragma unroll
        for (int n4 = 0; n4 < 4; ++n4)
#pragma unroll
            for (int rg = 0; rg < 4; ++rg)
                OP[w][mi * 16 + quad * 4 + rg][n4 * 16 + l15] = Oacc[mi][n4][rg];
    __syncthreads();

    // additive merge of the 4 wave-partials; write ctx bf16 (b,t,c)
    const int ii = tid >> 3, ds = tid & 7;
    float l = ML[0][ii] + ML[1][ii] + ML[2][ii] + ML[3][ii];
    float O[8] = {};
#pragma unroll
    for (int wv = 0; wv < 4; ++wv) {
        float4 o0 = *(const float4*)&OP[wv][ii][ds * 8];
        float4 o1 = *(const float4*)&OP[wv][ii][ds * 8 + 4];
        O[0] += o0.x; O[1] += o0.y; O[2] += o0.z; O[3] += o0.w;
        O[4] += o1.x; O[5] += o1.y; O[6] += o1.z; O[7] += o1.w;
    }
    const float inv = 1.0f / l;
    const int b = bh >> 4, h = bh & 15;
    u16x8 o;
#pragma unroll
    for (int dd = 0; dd < 8; ++dd) o[dd] = f2bf(O[dd] * inv);
    *(u16x8*)&ctxb[((size_t)b * T_ + i0 + ii) * DM_ + h * 64 + ds * 8] = o;
}

// -------------------------------------------------------------------------
extern "C" void kernel_launch(void* const* d_in, const int* in_sizes, int n_in,
                              void* d_out, int out_size, void* d_ws, size_t ws_size,
                              hipStream_t stream)
{
    const float* x       = (const float*)d_in[0];
    const float* Wq      = (const float*)d_in[1];
    const float* Wk      = (const float*)d_in[2];
    const float* Wv      = (const float*)d_in[3];
    const float* Wo      = (const float*)d_in[4];
    const float* Wqm     = (const float*)d_in[5];
    const float* Wkm     = (const float*)d_in[6];
    const float* Wmetric = (const float*)d_in[7];
    const float* temp    = (const float*)d_in[8];
    float* out = (float*)d_out;
    float* ws  = (float*)d_ws;

    // fp32 region
    float* q_raw = ws;                                  // 1,048,576 f
    float* k_raw = q_raw + (size_t)BH_ * T_ * DH_;      // 1,048,576 f
    float* q2p   = k_raw + (size_t)BH_ * T_ * DH_;      //    16,384 f
    float* k2    = q2p   + (size_t)BH_ * T_;            //    16,384 f
    // u16 region
    unsigned short* xb    = (unsigned short*)(k2 + (size_t)BH_ * T_);
    unsigned short* wqb   = xb    + (size_t)DM_ * DM_;
    unsigned short* wkb   = wqb   + (size_t)DM_ * DM_;
    unsigned short* wvb   = wkb   + (size_t)DM_ * DM_;
    unsigned short* wob   = wvb   + (size_t)DM_ * DM_;
    unsigned short* a_hi  = wob   + (size_t)DM_ * DM_;
    unsigned short* a_lo  = a_hi  + (size_t)BH_ * T_ * D_;
    unsigned short* kmhi  = a_lo  + (size_t)BH_ * T_ * D_;
    unsigned short* kmlo  = kmhi  + (size_t)BH_ * T_ * D_;
    unsigned short* Urb   = kmlo  + (size_t)BH_ * T_ * D_;   // BH*4*T*32
    unsigned short* vT    = Urb   + (size_t)BH_ * R_ * T_ * D_;
    unsigned short* ctxb  = (unsigned short*)q_raw;  // q_raw dead after feat
    // total ~ 8.5 MB f32 + ~21 MB u16  (<< proven 59 MB)

    prep_kernel<<<dim3(16, 16, 5), 256, 0, stream>>>(
        x, Wq, Wk, Wv, Wo, xb, wqb, wkb, wvb, wob);
    mfma_gemm64<0><<<dim3(48, 16), 256, 0, stream>>>(
        xb, wqb, wkb, wvb, q_raw, k_raw, vT);
    feat_both<<<dim3(BH_ * T_ / 4, 2), 256, 0, stream>>>(
        q_raw, k_raw, Wqm, Wkm, Wmetric,
        a_hi, a_lo, kmhi, kmlo, q2p, k2, Urb);
    attn_mfma<<<dim3(T_ / 32, BH_), 256, 0, stream>>>(
        a_hi, a_lo, kmhi, kmlo, Urb, q2p, k2, temp, vT, ctxb);
    mfma_gemm64<1><<<dim3(16, 16), 256, 0, stream>>>(
        ctxb, wob, nullptr, nullptr, out, nullptr, nullptr);
}